// Round 1
// baseline (4086.885 us; speedup 1.0000x reference)
//
#include <hip/hip_runtime.h>

#define BB 4
#define NN 50000
#define DD 256
#define EE 800000
#define TAU_MIN_F 0.001f
#define MAX_CORR_F 0.15f

// ---------------- Kernel 1: x = keypoints + tau * (hand_tokens @ head_w + head_b)
// One wave (64 lanes) per row; lane l loads float4 at d = 4*l (64*16B = 1024B = one full row).
__global__ __launch_bounds__(256) void xpred_kernel(
    const float* __restrict__ kp, const float* __restrict__ ts,
    const float* __restrict__ ht, const float* __restrict__ hw,
    const float* __restrict__ hb, float* __restrict__ x)
{
    const int lane  = threadIdx.x & 63;
    const int wave  = (blockIdx.x * blockDim.x + threadIdx.x) >> 6;
    const int nwave = (gridDim.x * blockDim.x) >> 6;

    // Per-lane slice of head_w: rows 4*lane .. 4*lane+3  (fixed for the whole grid loop)
    const int d0 = lane * 4;
    float W[4][3];
#pragma unroll
    for (int j = 0; j < 4; ++j)
#pragma unroll
        for (int k = 0; k < 3; ++k)
            W[j][k] = hw[(d0 + j) * 3 + k];
    const float b0 = hb[0], b1 = hb[1], b2 = hb[2];

    for (int row = wave; row < BB * NN; row += nwave) {
        const float4 h = *(const float4*)(ht + (size_t)row * DD + d0);
        float a0 = h.x * W[0][0] + h.y * W[1][0] + h.z * W[2][0] + h.w * W[3][0];
        float a1 = h.x * W[0][1] + h.y * W[1][1] + h.z * W[2][1] + h.w * W[3][1];
        float a2 = h.x * W[0][2] + h.y * W[1][2] + h.z * W[2][2] + h.w * W[3][2];
#pragma unroll
        for (int off = 32; off > 0; off >>= 1) {
            a0 += __shfl_down(a0, off);
            a1 += __shfl_down(a1, off);
            a2 += __shfl_down(a2, off);
        }
        if (lane == 0) {
            const int b   = row / NN;
            const float tau = fmaxf(1.0f - ts[b], TAU_MIN_F);
            x[row * 3 + 0] = kp[row * 3 + 0] + tau * (a0 + b0);
            x[row * 3 + 1] = kp[row * 3 + 1] + tau * (a1 + b1);
            x[row * 3 + 2] = kp[row * 3 + 2] + tau * (a2 + b2);
        }
    }
}

// ---------------- Kernel 2: one XPBD Jacobi sweep over edges -> atomicAdd into delta
__global__ __launch_bounds__(256) void edge_kernel(
    const float* __restrict__ x, const int* __restrict__ ei,
    const float* __restrict__ L0, float* __restrict__ delta)
{
    const int e = blockIdx.x * blockDim.x + threadIdx.x;
    if (e >= EE) return;
    const int   s    = ei[e];
    const int   d    = ei[EE + e];
    const float rest = L0[e];

#pragma unroll
    for (int b = 0; b < BB; ++b) {
        const float* xs = x + ((size_t)b * NN + s) * 3;
        const float* xd = x + ((size_t)b * NN + d) * 3;
        const float dx = xs[0] - xd[0];
        const float dy = xs[1] - xd[1];
        const float dz = xs[2] - xd[2];
        const float dist = sqrtf(dx * dx + dy * dy + dz * dz);
        const float C    = dist - rest;
        const float inv  = 1.0f / (dist + 1e-9f);
        const float dl   = -C * 0.5f;            // denom = w_i + w_j + alpha + 1e-9 == 2.0f in fp32
        float cx = fminf(fmaxf(dl * (dx * inv), -MAX_CORR_F), MAX_CORR_F);
        float cy = fminf(fmaxf(dl * (dy * inv), -MAX_CORR_F), MAX_CORR_F);
        float cz = fminf(fmaxf(dl * (dz * inv), -MAX_CORR_F), MAX_CORR_F);
        float* ps = delta + ((size_t)b * NN + s) * 3;
        float* pd = delta + ((size_t)b * NN + d) * 3;
        atomicAdd(ps + 0,  cx);
        atomicAdd(ps + 1,  cy);
        atomicAdd(ps + 2,  cz);
        atomicAdd(pd + 0, -cx);
        atomicAdd(pd + 1, -cy);
        atomicAdd(pd + 2, -cz);
    }
}

// ---------------- Kernel 3: x += delta; delta = 0 (for next Jacobi sweep)
__global__ __launch_bounds__(256) void apply_kernel(
    float* __restrict__ x, float* __restrict__ delta)
{
    const int i = blockIdx.x * blockDim.x + threadIdx.x;
    if (i >= BB * NN * 3) return;
    x[i] += delta[i];
    delta[i] = 0.0f;
}

// ---------------- Kernel 4 (last iter): out = (x + delta - kp) / tau
__global__ __launch_bounds__(256) void final_kernel(
    const float* __restrict__ x, const float* __restrict__ delta,
    const float* __restrict__ kp, const float* __restrict__ ts,
    float* __restrict__ out)
{
    const int i = blockIdx.x * blockDim.x + threadIdx.x;
    if (i >= BB * NN * 3) return;
    const int b = i / (NN * 3);
    const float tau = fmaxf(1.0f - ts[b], TAU_MIN_F);
    out[i] = (x[i] + delta[i] - kp[i]) / tau;
}

extern "C" void kernel_launch(void* const* d_in, const int* in_sizes, int n_in,
                              void* d_out, int out_size, void* d_ws, size_t ws_size,
                              hipStream_t stream)
{
    const float* kp = (const float*)d_in[0];   // (B,N,3)
    const float* ts = (const float*)d_in[1];   // (B,)
    const float* ht = (const float*)d_in[2];   // (B,N,D)
    const float* hw = (const float*)d_in[3];   // (D,3)
    const float* hb = (const float*)d_in[4];   // (3,)
    const int*   ei = (const int*)d_in[5];     // (2,E)
    const float* L0 = (const float*)d_in[6];   // (E,)
    float* out = (float*)d_out;

    float* x     = (float*)d_ws;               // B*N*3 floats
    float* delta = x + (size_t)BB * NN * 3;    // B*N*3 floats

    const int nElem = BB * NN * 3;             // 600000
    hipMemsetAsync(delta, 0, (size_t)nElem * sizeof(float), stream);

    // GEMM+pred: 1024 blocks * 4 waves = 4096 waves, grid-stride over 200000 rows
    xpred_kernel<<<1024, 256, 0, stream>>>(kp, ts, ht, hw, hb, x);

    const int edgeBlocks = (EE + 255) / 256;
    const int elemBlocks = (nElem + 255) / 256;
    for (int it = 0; it < 4; ++it) {
        edge_kernel<<<edgeBlocks, 256, 0, stream>>>(x, ei, L0, delta);
        if (it < 3)
            apply_kernel<<<elemBlocks, 256, 0, stream>>>(x, delta);
        else
            final_kernel<<<elemBlocks, 256, 0, stream>>>(x, delta, kp, ts, out);
    }
}

// Round 2
// 910.931 us; speedup vs baseline: 4.4865x; 4.4865x over previous
//
#include <hip/hip_runtime.h>

#define BB 4
#define NN 50000
#define DD 256
#define EE 800000
#define TAU_MIN_F 0.001f
#define MAX_CORR_F 0.15f

// ---------------- Kernel 1: x = keypoints + tau * (hand_tokens @ head_w + head_b)
// One wave (64 lanes) per row; lane l loads float4 at d = 4*l (64*16B = 1024B = one full row).
__global__ __launch_bounds__(256) void xpred_kernel(
    const float* __restrict__ kp, const float* __restrict__ ts,
    const float* __restrict__ ht, const float* __restrict__ hw,
    const float* __restrict__ hb, float* __restrict__ x)
{
    const int lane  = threadIdx.x & 63;
    const int wave  = (blockIdx.x * blockDim.x + threadIdx.x) >> 6;
    const int nwave = (gridDim.x * blockDim.x) >> 6;

    const int d0 = lane * 4;
    float W[4][3];
#pragma unroll
    for (int j = 0; j < 4; ++j)
#pragma unroll
        for (int k = 0; k < 3; ++k)
            W[j][k] = hw[(d0 + j) * 3 + k];
    const float b0 = hb[0], b1 = hb[1], b2 = hb[2];

    for (int row = wave; row < BB * NN; row += nwave) {
        const float4 h = *(const float4*)(ht + (size_t)row * DD + d0);
        float a0 = h.x * W[0][0] + h.y * W[1][0] + h.z * W[2][0] + h.w * W[3][0];
        float a1 = h.x * W[0][1] + h.y * W[1][1] + h.z * W[2][1] + h.w * W[3][1];
        float a2 = h.x * W[0][2] + h.y * W[1][2] + h.z * W[2][2] + h.w * W[3][2];
#pragma unroll
        for (int off = 32; off > 0; off >>= 1) {
            a0 += __shfl_down(a0, off);
            a1 += __shfl_down(a1, off);
            a2 += __shfl_down(a2, off);
        }
        if (lane == 0) {
            const int b   = row / NN;
            const float tau = fmaxf(1.0f - ts[b], TAU_MIN_F);
            x[row * 3 + 0] = kp[row * 3 + 0] + tau * (a0 + b0);
            x[row * 3 + 1] = kp[row * 3 + 1] + tau * (a1 + b1);
            x[row * 3 + 2] = kp[row * 3 + 2] + tau * (a2 + b2);
        }
    }
}

// ---------------- CSR build step 1: degree histogram
__global__ __launch_bounds__(256) void hist_kernel(
    const int* __restrict__ ei, int* __restrict__ counts)
{
    const int e = blockIdx.x * blockDim.x + threadIdx.x;
    if (e >= EE) return;
    atomicAdd(&counts[ei[e]], 1);
    atomicAdd(&counts[ei[EE + e]], 1);
}

// ---------------- CSR build step 2: exclusive scan (single block, 1024 threads)
// offsets[0]=0, offsets[i+1]=inclusive(i); cursor[i]=exclusive(i)
__global__ __launch_bounds__(1024) void scan_kernel(
    const int* __restrict__ counts, int* __restrict__ offsets, int* __restrict__ cursor)
{
    __shared__ int lds[1024];
    __shared__ int carry_s;
    if (threadIdx.x == 0) { carry_s = 0; offsets[0] = 0; }
    __syncthreads();
    for (int base = 0; base < NN; base += 1024) {
        const int i = base + (int)threadIdx.x;
        const int v = (i < NN) ? counts[i] : 0;
        lds[threadIdx.x] = v;
        __syncthreads();
        // Hillis-Steele inclusive scan
        for (int off = 1; off < 1024; off <<= 1) {
            int t = (threadIdx.x >= (unsigned)off) ? lds[threadIdx.x - off] : 0;
            __syncthreads();
            lds[threadIdx.x] += t;
            __syncthreads();
        }
        const int incl = lds[threadIdx.x];
        const int carry = carry_s;
        if (i < NN) {
            offsets[i + 1] = carry + incl;
            cursor[i]      = carry + incl - v;   // exclusive
        }
        __syncthreads();
        if (threadIdx.x == 1023) carry_s = carry + incl;
        __syncthreads();
    }
}

// ---------------- CSR build step 3: scatter adjacency entries {nbr, rest}
__global__ __launch_bounds__(256) void scatter_kernel(
    const int* __restrict__ ei, const float* __restrict__ L0,
    int* __restrict__ cursor, int2* __restrict__ adj)
{
    const int e = blockIdx.x * blockDim.x + threadIdx.x;
    if (e >= EE) return;
    const int s = ei[e];
    const int d = ei[EE + e];
    const int r = __float_as_int(L0[e]);
    int p = atomicAdd(&cursor[s], 1);
    adj[p] = make_int2(d, r);
    p = atomicAdd(&cursor[d], 1);
    adj[p] = make_int2(s, r);
}

// ---------------- One Jacobi XPBD sweep, gather form. Thread per (node, batch).
// For node i, neighbor j: diff = x[i]-x[j] -> correction is always +clip(dl*n)
// (clip is odd; n flips sign with diff; so src/dst roles need no sign flag).
__global__ __launch_bounds__(256) void gather_kernel(
    const float* __restrict__ xin, float* __restrict__ xout,
    const int* __restrict__ offsets, const int2* __restrict__ adj,
    const float* __restrict__ kp, const float* __restrict__ ts,
    float* __restrict__ out, int final_iter)
{
    const int node = blockIdx.x * blockDim.x + threadIdx.x;
    if (node >= NN) return;
    const int b = blockIdx.y;
    const float* __restrict__ xb = xin + (size_t)b * NN * 3;

    const float x0 = xb[node * 3 + 0];
    const float x1 = xb[node * 3 + 1];
    const float x2 = xb[node * 3 + 2];
    float a0 = x0, a1 = x1, a2 = x2;

    const int beg = offsets[node];
    const int end = offsets[node + 1];
    for (int k = beg; k < end; ++k) {
        const int2 ent = adj[k];
        const float* xn = xb + (size_t)ent.x * 3;
        const float dx = x0 - xn[0];
        const float dy = x1 - xn[1];
        const float dz = x2 - xn[2];
        const float dist = sqrtf(dx * dx + dy * dy + dz * dz);
        const float rest = __int_as_float(ent.y);
        const float s = (-(dist - rest) * 0.5f) / (dist + 1e-9f);
        a0 += fminf(fmaxf(s * dx, -MAX_CORR_F), MAX_CORR_F);
        a1 += fminf(fmaxf(s * dy, -MAX_CORR_F), MAX_CORR_F);
        a2 += fminf(fmaxf(s * dz, -MAX_CORR_F), MAX_CORR_F);
    }

    const size_t o = ((size_t)b * NN + node) * 3;
    if (!final_iter) {
        xout[o + 0] = a0;
        xout[o + 1] = a1;
        xout[o + 2] = a2;
    } else {
        const float tau = fmaxf(1.0f - ts[b], TAU_MIN_F);
        const float it  = 1.0f / tau;
        out[o + 0] = (a0 - kp[o + 0]) * it;
        out[o + 1] = (a1 - kp[o + 1]) * it;
        out[o + 2] = (a2 - kp[o + 2]) * it;
    }
}

extern "C" void kernel_launch(void* const* d_in, const int* in_sizes, int n_in,
                              void* d_out, int out_size, void* d_ws, size_t ws_size,
                              hipStream_t stream)
{
    const float* kp = (const float*)d_in[0];   // (B,N,3)
    const float* ts = (const float*)d_in[1];   // (B,)
    const float* ht = (const float*)d_in[2];   // (B,N,D)
    const float* hw = (const float*)d_in[3];   // (D,3)
    const float* hb = (const float*)d_in[4];   // (3,)
    const int*   ei = (const int*)d_in[5];     // (2,E)
    const float* L0 = (const float*)d_in[6];   // (E,)
    float* out = (float*)d_out;

    // Workspace layout (adj first for 8B alignment)
    char* w = (char*)d_ws;
    int2*  adj     = (int2*)w;                       w += (size_t)2 * EE * sizeof(int2);   // 12.8 MB
    float* xA      = (float*)w;                      w += (size_t)BB * NN * 3 * sizeof(float);
    float* xB      = (float*)w;                      w += (size_t)BB * NN * 3 * sizeof(float);
    int*   counts  = (int*)w;                        w += (size_t)NN * sizeof(int);
    int*   offsets = (int*)w;                        w += (size_t)(NN + 1) * sizeof(int);
    int*   cursor  = (int*)w;

    hipMemsetAsync(counts, 0, (size_t)NN * sizeof(int), stream);

    // Stage 1: x_pred (HBM-bound GEMM, 205 MB read)
    xpred_kernel<<<1024, 256, 0, stream>>>(kp, ts, ht, hw, hb, xA);

    // CSR build
    const int edgeBlocks = (EE + 255) / 256;
    hist_kernel<<<edgeBlocks, 256, 0, stream>>>(ei, counts);
    scan_kernel<<<1, 1024, 0, stream>>>(counts, offsets, cursor);
    scatter_kernel<<<edgeBlocks, 256, 0, stream>>>(ei, L0, cursor, adj);

    // 4 Jacobi sweeps, ping-pong xA <-> xB, last fuses v_eff
    dim3 ggrid((NN + 255) / 256, BB);
    gather_kernel<<<ggrid, 256, 0, stream>>>(xA, xB, offsets, adj, kp, ts, out, 0);
    gather_kernel<<<ggrid, 256, 0, stream>>>(xB, xA, offsets, adj, kp, ts, out, 0);
    gather_kernel<<<ggrid, 256, 0, stream>>>(xA, xB, offsets, adj, kp, ts, out, 0);
    gather_kernel<<<ggrid, 256, 0, stream>>>(xB, xA, offsets, adj, kp, ts, out, 1);
}

// Round 3
// 857.591 us; speedup vs baseline: 4.7655x; 1.0622x over previous
//
#include <hip/hip_runtime.h>

#define BB 4
#define NN 50000
#define DD 256
#define EE 800000
#define TAU_MIN_F 0.001f
#define MAX_CORR_F 0.15f
#define SCAN_BLOCKS ((NN + 255) / 256)   // 196

// ---------------- Kernel 1: x = keypoints + tau * (hand_tokens @ head_w + head_b)
// One wave per row; lane l loads float4 at d = 4*l (64*16B = 1024B = one full row).
// x is written PADDED to stride 4 (float4) for fast gather loads.
__global__ __launch_bounds__(256) void xpred_kernel(
    const float* __restrict__ kp, const float* __restrict__ ts,
    const float* __restrict__ ht, const float* __restrict__ hw,
    const float* __restrict__ hb, float4* __restrict__ x)
{
    const int lane  = threadIdx.x & 63;
    const int wave  = (blockIdx.x * blockDim.x + threadIdx.x) >> 6;
    const int nwave = (gridDim.x * blockDim.x) >> 6;

    const int d0 = lane * 4;
    float W[4][3];
#pragma unroll
    for (int j = 0; j < 4; ++j)
#pragma unroll
        for (int k = 0; k < 3; ++k)
            W[j][k] = hw[(d0 + j) * 3 + k];
    const float b0 = hb[0], b1 = hb[1], b2 = hb[2];

    for (int row = wave; row < BB * NN; row += nwave) {
        const float4 h = *(const float4*)(ht + (size_t)row * DD + d0);
        float a0 = h.x * W[0][0] + h.y * W[1][0] + h.z * W[2][0] + h.w * W[3][0];
        float a1 = h.x * W[0][1] + h.y * W[1][1] + h.z * W[2][1] + h.w * W[3][1];
        float a2 = h.x * W[0][2] + h.y * W[1][2] + h.z * W[2][2] + h.w * W[3][2];
#pragma unroll
        for (int off = 32; off > 0; off >>= 1) {
            a0 += __shfl_down(a0, off);
            a1 += __shfl_down(a1, off);
            a2 += __shfl_down(a2, off);
        }
        if (lane == 0) {
            const int b   = row / NN;
            const float tau = fmaxf(1.0f - ts[b], TAU_MIN_F);
            float4 v;
            v.x = kp[row * 3 + 0] + tau * (a0 + b0);
            v.y = kp[row * 3 + 1] + tau * (a1 + b1);
            v.z = kp[row * 3 + 2] + tau * (a2 + b2);
            v.w = 0.0f;
            x[row] = v;
        }
    }
}

// ---------------- CSR build step 1: degree histogram
__global__ __launch_bounds__(256) void hist_kernel(
    const int* __restrict__ ei, int* __restrict__ counts)
{
    const int e = blockIdx.x * blockDim.x + threadIdx.x;
    if (e >= EE) return;
    atomicAdd(&counts[ei[e]], 1);
    atomicAdd(&counts[ei[EE + e]], 1);
}

// ---------------- CSR build step 2a: per-block inclusive scan + block sums
__global__ __launch_bounds__(256) void scanA_kernel(
    const int* __restrict__ counts, int* __restrict__ tmpIncl, int* __restrict__ blockSums)
{
    __shared__ int lds[256];
    const int i = blockIdx.x * 256 + threadIdx.x;
    const int v = (i < NN) ? counts[i] : 0;
    lds[threadIdx.x] = v;
    __syncthreads();
#pragma unroll
    for (int off = 1; off < 256; off <<= 1) {
        const int t = (threadIdx.x >= (unsigned)off) ? lds[threadIdx.x - off] : 0;
        __syncthreads();
        lds[threadIdx.x] += t;
        __syncthreads();
    }
    if (i < NN) tmpIncl[i] = lds[threadIdx.x];
    if (threadIdx.x == 255) blockSums[blockIdx.x] = lds[255];
}

// ---------------- CSR build step 2b: exclusive scan of block sums (196 <= 256)
__global__ __launch_bounds__(256) void scanB_kernel(
    const int* __restrict__ blockSums, int* __restrict__ blockBase)
{
    __shared__ int lds[256];
    const int v = (threadIdx.x < SCAN_BLOCKS) ? blockSums[threadIdx.x] : 0;
    lds[threadIdx.x] = v;
    __syncthreads();
#pragma unroll
    for (int off = 1; off < 256; off <<= 1) {
        const int t = (threadIdx.x >= (unsigned)off) ? lds[threadIdx.x - off] : 0;
        __syncthreads();
        lds[threadIdx.x] += t;
        __syncthreads();
    }
    if (threadIdx.x < SCAN_BLOCKS) blockBase[threadIdx.x] = lds[threadIdx.x] - v;
}

// ---------------- CSR build step 2c: combine -> offsets, cursor
__global__ __launch_bounds__(256) void scanC_kernel(
    const int* __restrict__ counts, const int* __restrict__ tmpIncl,
    const int* __restrict__ blockBase, int* __restrict__ offsets, int* __restrict__ cursor)
{
    const int i = blockIdx.x * 256 + threadIdx.x;
    if (i == 0) offsets[0] = 0;
    if (i < NN) {
        const int incl = tmpIncl[i] + blockBase[blockIdx.x];
        offsets[i + 1] = incl;
        cursor[i]      = incl - counts[i];
    }
}

// ---------------- CSR build step 3: scatter adjacency entries {nbr, rest}
__global__ __launch_bounds__(256) void scatter_kernel(
    const int* __restrict__ ei, const float* __restrict__ L0,
    int* __restrict__ cursor, int2* __restrict__ adj)
{
    const int e = blockIdx.x * blockDim.x + threadIdx.x;
    if (e >= EE) return;
    const int s = ei[e];
    const int d = ei[EE + e];
    const int r = __float_as_int(L0[e]);
    int p = atomicAdd(&cursor[s], 1);
    adj[p] = make_int2(d, r);
    p = atomicAdd(&cursor[d], 1);
    adj[p] = make_int2(s, r);
}

// ---------------- One Jacobi XPBD sweep, gather form. Thread per (node, batch).
// x padded to float4 stride: one dwordx4 load per neighbor.
__global__ __launch_bounds__(256) void gather_kernel(
    const float4* __restrict__ xin, float4* __restrict__ xout,
    const int* __restrict__ offsets, const int2* __restrict__ adj,
    const float* __restrict__ kp, const float* __restrict__ ts,
    float* __restrict__ out, int final_iter)
{
    const int node = blockIdx.x * blockDim.x + threadIdx.x;
    if (node >= NN) return;
    const int b = blockIdx.y;
    const float4* __restrict__ xb = xin + (size_t)b * NN;

    const float4 xc = xb[node];
    float a0 = xc.x, a1 = xc.y, a2 = xc.z;

    const int beg = offsets[node];
    const int end = offsets[node + 1];
    for (int k = beg; k < end; ++k) {
        const int2 ent = adj[k];
        const float4 xn = xb[ent.x];
        const float dx = xc.x - xn.x;
        const float dy = xc.y - xn.y;
        const float dz = xc.z - xn.z;
        const float dist = sqrtf(dx * dx + dy * dy + dz * dz);
        const float s = (__int_as_float(ent.y) - dist) * 0.5f / (dist + 1e-9f);
        a0 += fminf(fmaxf(s * dx, -MAX_CORR_F), MAX_CORR_F);
        a1 += fminf(fmaxf(s * dy, -MAX_CORR_F), MAX_CORR_F);
        a2 += fminf(fmaxf(s * dz, -MAX_CORR_F), MAX_CORR_F);
    }

    if (!final_iter) {
        float4 v; v.x = a0; v.y = a1; v.z = a2; v.w = 0.0f;
        xout[(size_t)b * NN + node] = v;
    } else {
        const size_t o = ((size_t)b * NN + node) * 3;
        const float tau = fmaxf(1.0f - ts[b], TAU_MIN_F);
        const float it  = 1.0f / tau;
        out[o + 0] = (a0 - kp[o + 0]) * it;
        out[o + 1] = (a1 - kp[o + 1]) * it;
        out[o + 2] = (a2 - kp[o + 2]) * it;
    }
}

extern "C" void kernel_launch(void* const* d_in, const int* in_sizes, int n_in,
                              void* d_out, int out_size, void* d_ws, size_t ws_size,
                              hipStream_t stream)
{
    const float* kp = (const float*)d_in[0];   // (B,N,3)
    const float* ts = (const float*)d_in[1];   // (B,)
    const float* ht = (const float*)d_in[2];   // (B,N,D)
    const float* hw = (const float*)d_in[3];   // (D,3)
    const float* hb = (const float*)d_in[4];   // (3,)
    const int*   ei = (const int*)d_in[5];     // (2,E)
    const float* L0 = (const float*)d_in[6];   // (E,)
    float* out = (float*)d_out;

    // Workspace layout
    char* w = (char*)d_ws;
    int2*   adj       = (int2*)w;              w += (size_t)2 * EE * sizeof(int2);       // 12.8 MB
    float4* xA        = (float4*)w;            w += (size_t)BB * NN * sizeof(float4);    // 3.2 MB
    float4* xB        = (float4*)w;            w += (size_t)BB * NN * sizeof(float4);    // 3.2 MB
    int*    counts    = (int*)w;               w += (size_t)NN * sizeof(int);
    int*    tmpIncl   = (int*)w;               w += (size_t)NN * sizeof(int);
    int*    offsets   = (int*)w;               w += (size_t)(NN + 1) * sizeof(int);
    int*    cursor    = (int*)w;               w += (size_t)NN * sizeof(int);
    int*    blockSums = (int*)w;               w += (size_t)SCAN_BLOCKS * sizeof(int);
    int*    blockBase = (int*)w;

    hipMemsetAsync(counts, 0, (size_t)NN * sizeof(int), stream);

    // Stage 1: x_pred (HBM-bound, 205 MB read)
    xpred_kernel<<<1024, 256, 0, stream>>>(kp, ts, ht, hw, hb, xA);

    // CSR build
    const int edgeBlocks = (EE + 255) / 256;
    hist_kernel<<<edgeBlocks, 256, 0, stream>>>(ei, counts);
    scanA_kernel<<<SCAN_BLOCKS, 256, 0, stream>>>(counts, tmpIncl, blockSums);
    scanB_kernel<<<1, 256, 0, stream>>>(blockSums, blockBase);
    scanC_kernel<<<SCAN_BLOCKS, 256, 0, stream>>>(counts, tmpIncl, blockBase, offsets, cursor);
    scatter_kernel<<<edgeBlocks, 256, 0, stream>>>(ei, L0, cursor, adj);

    // 4 Jacobi sweeps, ping-pong xA <-> xB, last fuses v_eff
    dim3 ggrid(SCAN_BLOCKS, BB);
    gather_kernel<<<ggrid, 256, 0, stream>>>(xA, xB, offsets, adj, kp, ts, out, 0);
    gather_kernel<<<ggrid, 256, 0, stream>>>(xB, xA, offsets, adj, kp, ts, out, 0);
    gather_kernel<<<ggrid, 256, 0, stream>>>(xA, xB, offsets, adj, kp, ts, out, 0);
    gather_kernel<<<ggrid, 256, 0, stream>>>(xB, xA, offsets, adj, kp, ts, out, 1);
}

// Round 4
// 665.403 us; speedup vs baseline: 6.1420x; 1.2888x over previous
//
#include <hip/hip_runtime.h>

#define BB 4
#define NN 50000
#define DD 256
#define EE 800000
#define TAU_MIN_F 0.001f
#define MAX_CORR_F 0.15f
#define SCAN_BLOCKS ((NN + 255) / 256)   // 196

// ---------------- Kernel 1: x = keypoints + tau * (hand_tokens @ head_w + head_b)
// One wave per work item i = node*4 + b (node-major, batch-minor). Lane l loads
// float4 at d = 4*l (64*16B = 1024B = one full ht row). Writes x[i] directly in
// the padded node-major layout; a block's 4 waves cover one node's 64B line.
__global__ __launch_bounds__(256) void xpred_kernel(
    const float* __restrict__ kp, const float* __restrict__ ts,
    const float* __restrict__ ht, const float* __restrict__ hw,
    const float* __restrict__ hb, float4* __restrict__ x)
{
    const int lane  = threadIdx.x & 63;
    const int wave  = (blockIdx.x * blockDim.x + threadIdx.x) >> 6;
    const int nwave = (gridDim.x * blockDim.x) >> 6;

    const int d0 = lane * 4;
    float W[4][3];
#pragma unroll
    for (int j = 0; j < 4; ++j)
#pragma unroll
        for (int k = 0; k < 3; ++k)
            W[j][k] = hw[(d0 + j) * 3 + k];
    const float b0 = hb[0], b1 = hb[1], b2 = hb[2];

    for (int i = wave; i < BB * NN; i += nwave) {
        const int node = i >> 2;
        const int b    = i & 3;
        const int row  = b * NN + node;           // ht/kp row in (b, n) order
        const float4 h = *(const float4*)(ht + (size_t)row * DD + d0);
        float a0 = h.x * W[0][0] + h.y * W[1][0] + h.z * W[2][0] + h.w * W[3][0];
        float a1 = h.x * W[0][1] + h.y * W[1][1] + h.z * W[2][1] + h.w * W[3][1];
        float a2 = h.x * W[0][2] + h.y * W[1][2] + h.z * W[2][2] + h.w * W[3][2];
#pragma unroll
        for (int off = 32; off > 0; off >>= 1) {
            a0 += __shfl_down(a0, off);
            a1 += __shfl_down(a1, off);
            a2 += __shfl_down(a2, off);
        }
        if (lane == 0) {
            const float tau = fmaxf(1.0f - ts[b], TAU_MIN_F);
            float4 v;
            v.x = kp[row * 3 + 0] + tau * (a0 + b0);
            v.y = kp[row * 3 + 1] + tau * (a1 + b1);
            v.z = kp[row * 3 + 2] + tau * (a2 + b2);
            v.w = 0.0f;
            x[i] = v;                             // i == node*4 + b
        }
    }
}

// ---------------- CSR build step 1: degree histogram
__global__ __launch_bounds__(256) void hist_kernel(
    const int* __restrict__ ei, int* __restrict__ counts)
{
    const int e = blockIdx.x * blockDim.x + threadIdx.x;
    if (e >= EE) return;
    atomicAdd(&counts[ei[e]], 1);
    atomicAdd(&counts[ei[EE + e]], 1);
}

// ---------------- CSR build step 2a: per-block inclusive scan + block sums
__global__ __launch_bounds__(256) void scanA_kernel(
    const int* __restrict__ counts, int* __restrict__ tmpIncl, int* __restrict__ blockSums)
{
    __shared__ int lds[256];
    const int i = blockIdx.x * 256 + threadIdx.x;
    const int v = (i < NN) ? counts[i] : 0;
    lds[threadIdx.x] = v;
    __syncthreads();
#pragma unroll
    for (int off = 1; off < 256; off <<= 1) {
        const int t = (threadIdx.x >= (unsigned)off) ? lds[threadIdx.x - off] : 0;
        __syncthreads();
        lds[threadIdx.x] += t;
        __syncthreads();
    }
    if (i < NN) tmpIncl[i] = lds[threadIdx.x];
    if (threadIdx.x == 255) blockSums[blockIdx.x] = lds[255];
}

// ---------------- CSR build step 2b: exclusive scan of block sums (196 <= 256)
__global__ __launch_bounds__(256) void scanB_kernel(
    const int* __restrict__ blockSums, int* __restrict__ blockBase)
{
    __shared__ int lds[256];
    const int v = (threadIdx.x < SCAN_BLOCKS) ? blockSums[threadIdx.x] : 0;
    lds[threadIdx.x] = v;
    __syncthreads();
#pragma unroll
    for (int off = 1; off < 256; off <<= 1) {
        const int t = (threadIdx.x >= (unsigned)off) ? lds[threadIdx.x - off] : 0;
        __syncthreads();
        lds[threadIdx.x] += t;
        __syncthreads();
    }
    if (threadIdx.x < SCAN_BLOCKS) blockBase[threadIdx.x] = lds[threadIdx.x] - v;
}

// ---------------- CSR build step 2c: combine -> offsets, cursor
__global__ __launch_bounds__(256) void scanC_kernel(
    const int* __restrict__ counts, const int* __restrict__ tmpIncl,
    const int* __restrict__ blockBase, int* __restrict__ offsets, int* __restrict__ cursor)
{
    const int i = blockIdx.x * 256 + threadIdx.x;
    if (i == 0) offsets[0] = 0;
    if (i < NN) {
        const int incl = tmpIncl[i] + blockBase[blockIdx.x];
        offsets[i + 1] = incl;
        cursor[i]      = incl - counts[i];
    }
}

// ---------------- CSR build step 3: scatter adjacency entries {nbr, rest}
__global__ __launch_bounds__(256) void scatter_kernel(
    const int* __restrict__ ei, const float* __restrict__ L0,
    int* __restrict__ cursor, int2* __restrict__ adj)
{
    const int e = blockIdx.x * blockDim.x + threadIdx.x;
    if (e >= EE) return;
    const int s = ei[e];
    const int d = ei[EE + e];
    const int r = __float_as_int(L0[e]);
    int p = atomicAdd(&cursor[s], 1);
    adj[p] = make_int2(d, r);
    p = atomicAdd(&cursor[d], 1);
    adj[p] = make_int2(s, r);
}

// ---------------- One Jacobi XPBD sweep, gather form, batch-quad mapping.
// tid -> node = tid>>2, b = tid&3: a quad of lanes shares one node. Neighbor
// loads are one coalesced 64B line per quad; adj/offsets loads are quad-uniform
// (hardware-merged); a wave's 16 nodes have contiguous CSR ranges.
__global__ __launch_bounds__(256) void gather_kernel(
    const float4* __restrict__ xin, float4* __restrict__ xout,
    const int* __restrict__ offsets, const int2* __restrict__ adj,
    const float* __restrict__ kp, const float* __restrict__ ts,
    float* __restrict__ out, int final_iter)
{
    const int tid  = blockIdx.x * blockDim.x + threadIdx.x;
    const int node = tid >> 2;
    const int b    = tid & 3;
    if (node >= NN) return;

    const float4 xc = xin[tid];                   // tid == node*4 + b
    float a0 = xc.x, a1 = xc.y, a2 = xc.z;

    const int beg = offsets[node];
    const int end = offsets[node + 1];
    for (int k = beg; k < end; ++k) {
        const int2 ent = adj[k];                  // quad-uniform
        const float4 xn = xin[ent.x * 4 + b];     // quad-coalesced 64B
        const float dx = xc.x - xn.x;
        const float dy = xc.y - xn.y;
        const float dz = xc.z - xn.z;
        const float dist = sqrtf(dx * dx + dy * dy + dz * dz);
        const float s = (__int_as_float(ent.y) - dist) * 0.5f / (dist + 1e-9f);
        a0 += fminf(fmaxf(s * dx, -MAX_CORR_F), MAX_CORR_F);
        a1 += fminf(fmaxf(s * dy, -MAX_CORR_F), MAX_CORR_F);
        a2 += fminf(fmaxf(s * dz, -MAX_CORR_F), MAX_CORR_F);
    }

    if (!final_iter) {
        float4 v; v.x = a0; v.y = a1; v.z = a2; v.w = 0.0f;
        xout[tid] = v;
    } else {
        const int row = b * NN + node;            // out is (b, n, 3)
        const float tau = fmaxf(1.0f - ts[b], TAU_MIN_F);
        const float it  = 1.0f / tau;
        out[row * 3 + 0] = (a0 - kp[row * 3 + 0]) * it;
        out[row * 3 + 1] = (a1 - kp[row * 3 + 1]) * it;
        out[row * 3 + 2] = (a2 - kp[row * 3 + 2]) * it;
    }
}

extern "C" void kernel_launch(void* const* d_in, const int* in_sizes, int n_in,
                              void* d_out, int out_size, void* d_ws, size_t ws_size,
                              hipStream_t stream)
{
    const float* kp = (const float*)d_in[0];   // (B,N,3)
    const float* ts = (const float*)d_in[1];   // (B,)
    const float* ht = (const float*)d_in[2];   // (B,N,D)
    const float* hw = (const float*)d_in[3];   // (D,3)
    const float* hb = (const float*)d_in[4];   // (3,)
    const int*   ei = (const int*)d_in[5];     // (2,E)
    const float* L0 = (const float*)d_in[6];   // (E,)
    float* out = (float*)d_out;

    // Workspace layout
    char* w = (char*)d_ws;
    int2*   adj       = (int2*)w;              w += (size_t)2 * EE * sizeof(int2);       // 12.8 MB
    float4* xA        = (float4*)w;            w += (size_t)BB * NN * sizeof(float4);    // 3.2 MB
    float4* xB        = (float4*)w;            w += (size_t)BB * NN * sizeof(float4);    // 3.2 MB
    int*    counts    = (int*)w;               w += (size_t)NN * sizeof(int);
    int*    tmpIncl   = (int*)w;               w += (size_t)NN * sizeof(int);
    int*    offsets   = (int*)w;               w += (size_t)(NN + 1) * sizeof(int);
    int*    cursor    = (int*)w;               w += (size_t)NN * sizeof(int);
    int*    blockSums = (int*)w;               w += (size_t)SCAN_BLOCKS * sizeof(int);
    int*    blockBase = (int*)w;

    hipMemsetAsync(counts, 0, (size_t)NN * sizeof(int), stream);

    // Stage 1: x_pred (HBM-bound, 205 MB read)
    xpred_kernel<<<1024, 256, 0, stream>>>(kp, ts, ht, hw, hb, xA);

    // CSR build
    const int edgeBlocks = (EE + 255) / 256;
    hist_kernel<<<edgeBlocks, 256, 0, stream>>>(ei, counts);
    scanA_kernel<<<SCAN_BLOCKS, 256, 0, stream>>>(counts, tmpIncl, blockSums);
    scanB_kernel<<<1, 256, 0, stream>>>(blockSums, blockBase);
    scanC_kernel<<<SCAN_BLOCKS, 256, 0, stream>>>(counts, tmpIncl, blockBase, offsets, cursor);
    scatter_kernel<<<edgeBlocks, 256, 0, stream>>>(ei, L0, cursor, adj);

    // 4 Jacobi sweeps, ping-pong xA <-> xB, last fuses v_eff
    const int gatherBlocks = (BB * NN + 255) / 256;   // 782
    gather_kernel<<<gatherBlocks, 256, 0, stream>>>(xA, xB, offsets, adj, kp, ts, out, 0);
    gather_kernel<<<gatherBlocks, 256, 0, stream>>>(xB, xA, offsets, adj, kp, ts, out, 0);
    gather_kernel<<<gatherBlocks, 256, 0, stream>>>(xA, xB, offsets, adj, kp, ts, out, 0);
    gather_kernel<<<gatherBlocks, 256, 0, stream>>>(xB, xA, offsets, adj, kp, ts, out, 1);
}

// Round 5
// 597.719 us; speedup vs baseline: 6.8375x; 1.1132x over previous
//
#include <hip/hip_runtime.h>

#define BB 4
#define NN 50000
#define DD 256
#define EE 800000
#define TAU_MIN_F 0.001f
#define MAX_CORR_F 0.15f
#define SCAN_BLOCKS ((NN + 255) / 256)   // 196

// ---------------- Kernel 1: x = keypoints + tau * (hand_tokens @ head_w + head_b)
// One wave per work item i = node*4 + b (node-major, batch-minor). Lane l loads
// float4 at d = 4*l (64*16B = 1024B = one full ht row).
__global__ __launch_bounds__(256) void xpred_kernel(
    const float* __restrict__ kp, const float* __restrict__ ts,
    const float* __restrict__ ht, const float* __restrict__ hw,
    const float* __restrict__ hb, float4* __restrict__ x)
{
    const int lane  = threadIdx.x & 63;
    const int wave  = (blockIdx.x * blockDim.x + threadIdx.x) >> 6;
    const int nwave = (gridDim.x * blockDim.x) >> 6;

    const int d0 = lane * 4;
    float W[4][3];
#pragma unroll
    for (int j = 0; j < 4; ++j)
#pragma unroll
        for (int k = 0; k < 3; ++k)
            W[j][k] = hw[(d0 + j) * 3 + k];
    const float b0 = hb[0], b1 = hb[1], b2 = hb[2];

    for (int i = wave; i < BB * NN; i += nwave) {
        const int node = i >> 2;
        const int b    = i & 3;
        const int row  = b * NN + node;           // ht/kp row in (b, n) order
        const float4 h = *(const float4*)(ht + (size_t)row * DD + d0);
        float a0 = h.x * W[0][0] + h.y * W[1][0] + h.z * W[2][0] + h.w * W[3][0];
        float a1 = h.x * W[0][1] + h.y * W[1][1] + h.z * W[2][1] + h.w * W[3][1];
        float a2 = h.x * W[0][2] + h.y * W[1][2] + h.z * W[2][2] + h.w * W[3][2];
#pragma unroll
        for (int off = 32; off > 0; off >>= 1) {
            a0 += __shfl_down(a0, off);
            a1 += __shfl_down(a1, off);
            a2 += __shfl_down(a2, off);
        }
        if (lane == 0) {
            const float tau = fmaxf(1.0f - ts[b], TAU_MIN_F);
            float4 v;
            v.x = kp[row * 3 + 0] + tau * (a0 + b0);
            v.y = kp[row * 3 + 1] + tau * (a1 + b1);
            v.z = kp[row * 3 + 2] + tau * (a2 + b2);
            v.w = 0.0f;
            x[i] = v;                             // i == node*4 + b
        }
    }
}

// ---------------- CSR build step 1: degree histogram
__global__ __launch_bounds__(256) void hist_kernel(
    const int* __restrict__ ei, int* __restrict__ counts)
{
    const int e = blockIdx.x * blockDim.x + threadIdx.x;
    if (e >= EE) return;
    atomicAdd(&counts[ei[e]], 1);
    atomicAdd(&counts[ei[EE + e]], 1);
}

// ---------------- CSR build step 2a: per-block inclusive scan + block sums
__global__ __launch_bounds__(256) void scanA_kernel(
    const int* __restrict__ counts, int* __restrict__ tmpIncl, int* __restrict__ blockSums)
{
    __shared__ int lds[256];
    const int i = blockIdx.x * 256 + threadIdx.x;
    const int v = (i < NN) ? counts[i] : 0;
    lds[threadIdx.x] = v;
    __syncthreads();
#pragma unroll
    for (int off = 1; off < 256; off <<= 1) {
        const int t = (threadIdx.x >= (unsigned)off) ? lds[threadIdx.x - off] : 0;
        __syncthreads();
        lds[threadIdx.x] += t;
        __syncthreads();
    }
    if (i < NN) tmpIncl[i] = lds[threadIdx.x];
    if (threadIdx.x == 255) blockSums[blockIdx.x] = lds[255];
}

// ---------------- CSR build step 2b: exclusive scan of block sums (196 <= 256)
__global__ __launch_bounds__(256) void scanB_kernel(
    const int* __restrict__ blockSums, int* __restrict__ blockBase)
{
    __shared__ int lds[256];
    const int v = (threadIdx.x < SCAN_BLOCKS) ? blockSums[threadIdx.x] : 0;
    lds[threadIdx.x] = v;
    __syncthreads();
#pragma unroll
    for (int off = 1; off < 256; off <<= 1) {
        const int t = (threadIdx.x >= (unsigned)off) ? lds[threadIdx.x - off] : 0;
        __syncthreads();
        lds[threadIdx.x] += t;
        __syncthreads();
    }
    if (threadIdx.x < SCAN_BLOCKS) blockBase[threadIdx.x] = lds[threadIdx.x] - v;
}

// ---------------- CSR build step 2c: combine -> offsets, cursor
__global__ __launch_bounds__(256) void scanC_kernel(
    const int* __restrict__ counts, const int* __restrict__ tmpIncl,
    const int* __restrict__ blockBase, int* __restrict__ offsets, int* __restrict__ cursor)
{
    const int i = blockIdx.x * 256 + threadIdx.x;
    if (i == 0) offsets[0] = 0;
    if (i < NN) {
        const int incl = tmpIncl[i] + blockBase[blockIdx.x];
        offsets[i + 1] = incl;
        cursor[i]      = incl - counts[i];
    }
}

// ---------------- CSR build step 3: scatter adjacency entries {nbr, rest}
__global__ __launch_bounds__(256) void scatter_kernel(
    const int* __restrict__ ei, const float* __restrict__ L0,
    int* __restrict__ cursor, int2* __restrict__ adj)
{
    const int e = blockIdx.x * blockDim.x + threadIdx.x;
    if (e >= EE) return;
    const int s = ei[e];
    const int d = ei[EE + e];
    const int r = __float_as_int(L0[e]);
    int p = atomicAdd(&cursor[s], 1);
    adj[p] = make_int2(d, r);
    p = atomicAdd(&cursor[d], 1);
    adj[p] = make_int2(s, r);
}

// ---------------- One Jacobi XPBD sweep, gather form, 16 threads per node.
// tid -> b = tid&3 (batch), sub = (tid>>2)&3 (CSR-range stripe), node = tid>>4.
// 800000 threads = 12.5K waves: full latency-hiding occupancy. Neighbor x loads
// stay b-quad-coalesced (64B line); the 4 subs of a node read 4 consecutive adj
// entries. Partial clipped corrections reduced via shfl_xor(4/8) — exact math.
__global__ __launch_bounds__(256) void gather_kernel(
    const float4* __restrict__ xin, float4* __restrict__ xout,
    const int* __restrict__ offsets, const int2* __restrict__ adj,
    const float* __restrict__ kp, const float* __restrict__ ts,
    float* __restrict__ out, int final_iter)
{
    const int tid  = blockIdx.x * 256 + threadIdx.x;   // grid is exactly 16*NN
    const int b    = tid & 3;
    const int sub  = (tid >> 2) & 3;
    const int node = tid >> 4;

    const float4 xc = xin[(node << 2) + b];
    float a0 = 0.0f, a1 = 0.0f, a2 = 0.0f;            // correction only

    const int beg = offsets[node];
    const int end = offsets[node + 1];

    int k = beg + sub;
    // 2-way unrolled strided walk: two independent load pairs in flight
    for (; k + 4 < end; k += 8) {
        const int2 e0 = adj[k];
        const int2 e1 = adj[k + 4];
        const float4 n0 = xin[(e0.x << 2) + b];
        const float4 n1 = xin[(e1.x << 2) + b];
        {
            const float dx = xc.x - n0.x, dy = xc.y - n0.y, dz = xc.z - n0.z;
            const float dist = sqrtf(dx * dx + dy * dy + dz * dz);
            const float s = (__int_as_float(e0.y) - dist) * 0.5f / (dist + 1e-9f);
            a0 += fminf(fmaxf(s * dx, -MAX_CORR_F), MAX_CORR_F);
            a1 += fminf(fmaxf(s * dy, -MAX_CORR_F), MAX_CORR_F);
            a2 += fminf(fmaxf(s * dz, -MAX_CORR_F), MAX_CORR_F);
        }
        {
            const float dx = xc.x - n1.x, dy = xc.y - n1.y, dz = xc.z - n1.z;
            const float dist = sqrtf(dx * dx + dy * dy + dz * dz);
            const float s = (__int_as_float(e1.y) - dist) * 0.5f / (dist + 1e-9f);
            a0 += fminf(fmaxf(s * dx, -MAX_CORR_F), MAX_CORR_F);
            a1 += fminf(fmaxf(s * dy, -MAX_CORR_F), MAX_CORR_F);
            a2 += fminf(fmaxf(s * dz, -MAX_CORR_F), MAX_CORR_F);
        }
    }
    if (k < end) {
        const int2 e0 = adj[k];
        const float4 n0 = xin[(e0.x << 2) + b];
        const float dx = xc.x - n0.x, dy = xc.y - n0.y, dz = xc.z - n0.z;
        const float dist = sqrtf(dx * dx + dy * dy + dz * dz);
        const float s = (__int_as_float(e0.y) - dist) * 0.5f / (dist + 1e-9f);
        a0 += fminf(fmaxf(s * dx, -MAX_CORR_F), MAX_CORR_F);
        a1 += fminf(fmaxf(s * dy, -MAX_CORR_F), MAX_CORR_F);
        a2 += fminf(fmaxf(s * dz, -MAX_CORR_F), MAX_CORR_F);
    }

    // reduce the 4 sub-stripes (lanes differing in bits 2-3)
    a0 += __shfl_xor(a0, 4);  a0 += __shfl_xor(a0, 8);
    a1 += __shfl_xor(a1, 4);  a1 += __shfl_xor(a1, 8);
    a2 += __shfl_xor(a2, 4);  a2 += __shfl_xor(a2, 8);

    if (sub == 0) {
        if (!final_iter) {
            float4 v; v.x = xc.x + a0; v.y = xc.y + a1; v.z = xc.z + a2; v.w = 0.0f;
            xout[(node << 2) + b] = v;
        } else {
            const int row = b * NN + node;            // out is (b, n, 3)
            const float tau = fmaxf(1.0f - ts[b], TAU_MIN_F);
            const float it  = 1.0f / tau;
            out[row * 3 + 0] = (xc.x + a0 - kp[row * 3 + 0]) * it;
            out[row * 3 + 1] = (xc.y + a1 - kp[row * 3 + 1]) * it;
            out[row * 3 + 2] = (xc.z + a2 - kp[row * 3 + 2]) * it;
        }
    }
}

extern "C" void kernel_launch(void* const* d_in, const int* in_sizes, int n_in,
                              void* d_out, int out_size, void* d_ws, size_t ws_size,
                              hipStream_t stream)
{
    const float* kp = (const float*)d_in[0];   // (B,N,3)
    const float* ts = (const float*)d_in[1];   // (B,)
    const float* ht = (const float*)d_in[2];   // (B,N,D)
    const float* hw = (const float*)d_in[3];   // (D,3)
    const float* hb = (const float*)d_in[4];   // (3,)
    const int*   ei = (const int*)d_in[5];     // (2,E)
    const float* L0 = (const float*)d_in[6];   // (E,)
    float* out = (float*)d_out;

    // Workspace layout
    char* w = (char*)d_ws;
    int2*   adj       = (int2*)w;              w += (size_t)2 * EE * sizeof(int2);       // 12.8 MB
    float4* xA        = (float4*)w;            w += (size_t)BB * NN * sizeof(float4);    // 3.2 MB
    float4* xB        = (float4*)w;            w += (size_t)BB * NN * sizeof(float4);    // 3.2 MB
    int*    counts    = (int*)w;               w += (size_t)NN * sizeof(int);
    int*    tmpIncl   = (int*)w;               w += (size_t)NN * sizeof(int);
    int*    offsets   = (int*)w;               w += (size_t)(NN + 1) * sizeof(int);
    int*    cursor    = (int*)w;               w += (size_t)NN * sizeof(int);
    int*    blockSums = (int*)w;               w += (size_t)SCAN_BLOCKS * sizeof(int);
    int*    blockBase = (int*)w;

    hipMemsetAsync(counts, 0, (size_t)NN * sizeof(int), stream);

    // Stage 1: x_pred (HBM-bound, 205 MB read)
    xpred_kernel<<<1024, 256, 0, stream>>>(kp, ts, ht, hw, hb, xA);

    // CSR build
    const int edgeBlocks = (EE + 255) / 256;
    hist_kernel<<<edgeBlocks, 256, 0, stream>>>(ei, counts);
    scanA_kernel<<<SCAN_BLOCKS, 256, 0, stream>>>(counts, tmpIncl, blockSums);
    scanB_kernel<<<1, 256, 0, stream>>>(blockSums, blockBase);
    scanC_kernel<<<SCAN_BLOCKS, 256, 0, stream>>>(counts, tmpIncl, blockBase, offsets, cursor);
    scatter_kernel<<<edgeBlocks, 256, 0, stream>>>(ei, L0, cursor, adj);

    // 4 Jacobi sweeps, ping-pong xA <-> xB, last fuses v_eff
    const int gatherBlocks = (16 * NN) / 256;          // 3125, exact
    gather_kernel<<<gatherBlocks, 256, 0, stream>>>(xA, xB, offsets, adj, kp, ts, out, 0);
    gather_kernel<<<gatherBlocks, 256, 0, stream>>>(xB, xA, offsets, adj, kp, ts, out, 0);
    gather_kernel<<<gatherBlocks, 256, 0, stream>>>(xA, xB, offsets, adj, kp, ts, out, 0);
    gather_kernel<<<gatherBlocks, 256, 0, stream>>>(xB, xA, offsets, adj, kp, ts, out, 1);
}

// Round 6
// 536.140 us; speedup vs baseline: 7.6228x; 1.1149x over previous
//
#include <hip/hip_runtime.h>

#define BB 4
#define NN 50000
#define DD 256
#define EE 800000
#define TAU_MIN_F 0.001f
#define MAX_CORR_F 0.15f
#define SCAN_BLOCKS ((NN + 255) / 256)   // 196

#define NPART 8                          // one partition per XCD
#define PNODES (NN / NPART)              // 6250 nodes -> adj span ~1.6 MB, fits 4 MB L2
#define PS_CE 2048                       // edges per chunk
#define PS_NCHUNK ((EE + PS_CE - 1) / PS_CE)  // 391

// ---------------- Kernel 1: x = keypoints + tau * (hand_tokens @ head_w + head_b)
// One wave per work item i = node*4 + b (node-major, batch-minor). Lane l loads
// float4 at d = 4*l (64*16B = 1024B = one full ht row).
__global__ __launch_bounds__(256) void xpred_kernel(
    const float* __restrict__ kp, const float* __restrict__ ts,
    const float* __restrict__ ht, const float* __restrict__ hw,
    const float* __restrict__ hb, float4* __restrict__ x)
{
    const int lane  = threadIdx.x & 63;
    const int wave  = (blockIdx.x * blockDim.x + threadIdx.x) >> 6;
    const int nwave = (gridDim.x * blockDim.x) >> 6;

    const int d0 = lane * 4;
    float W[4][3];
#pragma unroll
    for (int j = 0; j < 4; ++j)
#pragma unroll
        for (int k = 0; k < 3; ++k)
            W[j][k] = hw[(d0 + j) * 3 + k];
    const float b0 = hb[0], b1 = hb[1], b2 = hb[2];

    for (int i = wave; i < BB * NN; i += nwave) {
        const int node = i >> 2;
        const int b    = i & 3;
        const int row  = b * NN + node;           // ht/kp row in (b, n) order
        const float4 h = *(const float4*)(ht + (size_t)row * DD + d0);
        float a0 = h.x * W[0][0] + h.y * W[1][0] + h.z * W[2][0] + h.w * W[3][0];
        float a1 = h.x * W[0][1] + h.y * W[1][1] + h.z * W[2][1] + h.w * W[3][1];
        float a2 = h.x * W[0][2] + h.y * W[1][2] + h.z * W[2][2] + h.w * W[3][2];
#pragma unroll
        for (int off = 32; off > 0; off >>= 1) {
            a0 += __shfl_down(a0, off);
            a1 += __shfl_down(a1, off);
            a2 += __shfl_down(a2, off);
        }
        if (lane == 0) {
            const float tau = fmaxf(1.0f - ts[b], TAU_MIN_F);
            float4 v;
            v.x = kp[row * 3 + 0] + tau * (a0 + b0);
            v.y = kp[row * 3 + 1] + tau * (a1 + b1);
            v.z = kp[row * 3 + 2] + tau * (a2 + b2);
            v.w = 0.0f;
            x[i] = v;                             // i == node*4 + b
        }
    }
}

// ---------------- CSR build step 1: degree histogram
__global__ __launch_bounds__(256) void hist_kernel(
    const int* __restrict__ ei, int* __restrict__ counts)
{
    const int e = blockIdx.x * blockDim.x + threadIdx.x;
    if (e >= EE) return;
    atomicAdd(&counts[ei[e]], 1);
    atomicAdd(&counts[ei[EE + e]], 1);
}

// ---------------- CSR build step 2a: per-block inclusive scan + block sums
__global__ __launch_bounds__(256) void scanA_kernel(
    const int* __restrict__ counts, int* __restrict__ tmpIncl, int* __restrict__ blockSums)
{
    __shared__ int lds[256];
    const int i = blockIdx.x * 256 + threadIdx.x;
    const int v = (i < NN) ? counts[i] : 0;
    lds[threadIdx.x] = v;
    __syncthreads();
#pragma unroll
    for (int off = 1; off < 256; off <<= 1) {
        const int t = (threadIdx.x >= (unsigned)off) ? lds[threadIdx.x - off] : 0;
        __syncthreads();
        lds[threadIdx.x] += t;
        __syncthreads();
    }
    if (i < NN) tmpIncl[i] = lds[threadIdx.x];
    if (threadIdx.x == 255) blockSums[blockIdx.x] = lds[255];
}

// ---------------- CSR build step 2b: exclusive scan of block sums (196 <= 256)
__global__ __launch_bounds__(256) void scanB_kernel(
    const int* __restrict__ blockSums, int* __restrict__ blockBase)
{
    __shared__ int lds[256];
    const int v = (threadIdx.x < SCAN_BLOCKS) ? blockSums[threadIdx.x] : 0;
    lds[threadIdx.x] = v;
    __syncthreads();
#pragma unroll
    for (int off = 1; off < 256; off <<= 1) {
        const int t = (threadIdx.x >= (unsigned)off) ? lds[threadIdx.x - off] : 0;
        __syncthreads();
        lds[threadIdx.x] += t;
        __syncthreads();
    }
    if (threadIdx.x < SCAN_BLOCKS) blockBase[threadIdx.x] = lds[threadIdx.x] - v;
}

// ---------------- CSR build step 2c: combine -> offsets, cursor
__global__ __launch_bounds__(256) void scanC_kernel(
    const int* __restrict__ counts, const int* __restrict__ tmpIncl,
    const int* __restrict__ blockBase, int* __restrict__ offsets, int* __restrict__ cursor)
{
    const int i = blockIdx.x * 256 + threadIdx.x;
    if (i == 0) offsets[0] = 0;
    if (i < NN) {
        const int incl = tmpIncl[i] + blockBase[blockIdx.x];
        offsets[i + 1] = incl;
        cursor[i]      = incl - counts[i];
    }
}

// ---------------- CSR build step 3: node-partitioned scatter.
// blockIdx.x = partition (fastest-varying -> XCD via round-robin dispatch);
// each block scans one 2048-edge chunk and writes only entries whose target
// node lies in its partition. Partition adj span ~1.6 MB stays L2-resident ->
// 64B lines fully populated before eviction (write-back ~12.8 MB total, was 101 MB).
__global__ __launch_bounds__(256) void pscatter_kernel(
    const int* __restrict__ ei, const float* __restrict__ L0,
    int* __restrict__ cursor, int2* __restrict__ adj)
{
    const int lo   = (int)blockIdx.x * PNODES;
    const int hi   = lo + PNODES;
    const int base = (int)blockIdx.y * PS_CE;
    const int eEnd = min(base + PS_CE, EE);
    for (int e = base + (int)threadIdx.x; e < eEnd; e += 256) {
        const int s = ei[e];
        const int d = ei[EE + e];
        const int r = __float_as_int(L0[e]);
        if (s >= lo && s < hi) {
            const int p = atomicAdd(&cursor[s], 1);
            adj[p] = make_int2(d, r);
        }
        if (d >= lo && d < hi) {
            const int p = atomicAdd(&cursor[d], 1);
            adj[p] = make_int2(s, r);
        }
    }
}

// ---------------- One Jacobi XPBD sweep, gather form, 16 threads per node.
// tid -> b = tid&3 (batch), sub = (tid>>2)&3 (CSR-range stripe), node = tid>>4.
__global__ __launch_bounds__(256) void gather_kernel(
    const float4* __restrict__ xin, float4* __restrict__ xout,
    const int* __restrict__ offsets, const int2* __restrict__ adj,
    const float* __restrict__ kp, const float* __restrict__ ts,
    float* __restrict__ out, int final_iter)
{
    const int tid  = blockIdx.x * 256 + threadIdx.x;   // grid is exactly 16*NN
    const int b    = tid & 3;
    const int sub  = (tid >> 2) & 3;
    const int node = tid >> 4;

    const float4 xc = xin[(node << 2) + b];
    float a0 = 0.0f, a1 = 0.0f, a2 = 0.0f;            // correction only

    const int beg = offsets[node];
    const int end = offsets[node + 1];

    int k = beg + sub;
    // 2-way unrolled strided walk: two independent load pairs in flight
    for (; k + 4 < end; k += 8) {
        const int2 e0 = adj[k];
        const int2 e1 = adj[k + 4];
        const float4 n0 = xin[(e0.x << 2) + b];
        const float4 n1 = xin[(e1.x << 2) + b];
        {
            const float dx = xc.x - n0.x, dy = xc.y - n0.y, dz = xc.z - n0.z;
            const float dist = sqrtf(dx * dx + dy * dy + dz * dz);
            const float s = (__int_as_float(e0.y) - dist) * 0.5f / (dist + 1e-9f);
            a0 += fminf(fmaxf(s * dx, -MAX_CORR_F), MAX_CORR_F);
            a1 += fminf(fmaxf(s * dy, -MAX_CORR_F), MAX_CORR_F);
            a2 += fminf(fmaxf(s * dz, -MAX_CORR_F), MAX_CORR_F);
        }
        {
            const float dx = xc.x - n1.x, dy = xc.y - n1.y, dz = xc.z - n1.z;
            const float dist = sqrtf(dx * dx + dy * dy + dz * dz);
            const float s = (__int_as_float(e1.y) - dist) * 0.5f / (dist + 1e-9f);
            a0 += fminf(fmaxf(s * dx, -MAX_CORR_F), MAX_CORR_F);
            a1 += fminf(fmaxf(s * dy, -MAX_CORR_F), MAX_CORR_F);
            a2 += fminf(fmaxf(s * dz, -MAX_CORR_F), MAX_CORR_F);
        }
    }
    if (k < end) {
        const int2 e0 = adj[k];
        const float4 n0 = xin[(e0.x << 2) + b];
        const float dx = xc.x - n0.x, dy = xc.y - n0.y, dz = xc.z - n0.z;
        const float dist = sqrtf(dx * dx + dy * dy + dz * dz);
        const float s = (__int_as_float(e0.y) - dist) * 0.5f / (dist + 1e-9f);
        a0 += fminf(fmaxf(s * dx, -MAX_CORR_F), MAX_CORR_F);
        a1 += fminf(fmaxf(s * dy, -MAX_CORR_F), MAX_CORR_F);
        a2 += fminf(fmaxf(s * dz, -MAX_CORR_F), MAX_CORR_F);
    }

    // reduce the 4 sub-stripes (lanes differing in bits 2-3)
    a0 += __shfl_xor(a0, 4);  a0 += __shfl_xor(a0, 8);
    a1 += __shfl_xor(a1, 4);  a1 += __shfl_xor(a1, 8);
    a2 += __shfl_xor(a2, 4);  a2 += __shfl_xor(a2, 8);

    if (sub == 0) {
        if (!final_iter) {
            float4 v; v.x = xc.x + a0; v.y = xc.y + a1; v.z = xc.z + a2; v.w = 0.0f;
            xout[(node << 2) + b] = v;
        } else {
            const int row = b * NN + node;            // out is (b, n, 3)
            const float tau = fmaxf(1.0f - ts[b], TAU_MIN_F);
            const float it  = 1.0f / tau;
            out[row * 3 + 0] = (xc.x + a0 - kp[row * 3 + 0]) * it;
            out[row * 3 + 1] = (xc.y + a1 - kp[row * 3 + 1]) * it;
            out[row * 3 + 2] = (xc.z + a2 - kp[row * 3 + 2]) * it;
        }
    }
}

extern "C" void kernel_launch(void* const* d_in, const int* in_sizes, int n_in,
                              void* d_out, int out_size, void* d_ws, size_t ws_size,
                              hipStream_t stream)
{
    const float* kp = (const float*)d_in[0];   // (B,N,3)
    const float* ts = (const float*)d_in[1];   // (B,)
    const float* ht = (const float*)d_in[2];   // (B,N,D)
    const float* hw = (const float*)d_in[3];   // (D,3)
    const float* hb = (const float*)d_in[4];   // (3,)
    const int*   ei = (const int*)d_in[5];     // (2,E)
    const float* L0 = (const float*)d_in[6];   // (E,)
    float* out = (float*)d_out;

    // Workspace layout
    char* w = (char*)d_ws;
    int2*   adj       = (int2*)w;              w += (size_t)2 * EE * sizeof(int2);       // 12.8 MB
    float4* xA        = (float4*)w;            w += (size_t)BB * NN * sizeof(float4);    // 3.2 MB
    float4* xB        = (float4*)w;            w += (size_t)BB * NN * sizeof(float4);    // 3.2 MB
    int*    counts    = (int*)w;               w += (size_t)NN * sizeof(int);
    int*    tmpIncl   = (int*)w;               w += (size_t)NN * sizeof(int);
    int*    offsets   = (int*)w;               w += (size_t)(NN + 1) * sizeof(int);
    int*    cursor    = (int*)w;               w += (size_t)NN * sizeof(int);
    int*    blockSums = (int*)w;               w += (size_t)SCAN_BLOCKS * sizeof(int);
    int*    blockBase = (int*)w;

    hipMemsetAsync(counts, 0, (size_t)NN * sizeof(int), stream);

    // Stage 1: x_pred (HBM-bound, 205 MB read)
    xpred_kernel<<<1024, 256, 0, stream>>>(kp, ts, ht, hw, hb, xA);

    // CSR build
    const int edgeBlocks = (EE + 255) / 256;
    hist_kernel<<<edgeBlocks, 256, 0, stream>>>(ei, counts);
    scanA_kernel<<<SCAN_BLOCKS, 256, 0, stream>>>(counts, tmpIncl, blockSums);
    scanB_kernel<<<1, 256, 0, stream>>>(blockSums, blockBase);
    scanC_kernel<<<SCAN_BLOCKS, 256, 0, stream>>>(counts, tmpIncl, blockBase, offsets, cursor);
    pscatter_kernel<<<dim3(NPART, PS_NCHUNK), 256, 0, stream>>>(ei, L0, cursor, adj);

    // 4 Jacobi sweeps, ping-pong xA <-> xB, last fuses v_eff
    const int gatherBlocks = (16 * NN) / 256;          // 3125, exact
    gather_kernel<<<gatherBlocks, 256, 0, stream>>>(xA, xB, offsets, adj, kp, ts, out, 0);
    gather_kernel<<<gatherBlocks, 256, 0, stream>>>(xB, xA, offsets, adj, kp, ts, out, 0);
    gather_kernel<<<gatherBlocks, 256, 0, stream>>>(xA, xB, offsets, adj, kp, ts, out, 0);
    gather_kernel<<<gatherBlocks, 256, 0, stream>>>(xB, xA, offsets, adj, kp, ts, out, 1);
}